// Round 5
// baseline (177.101 us; speedup 1.0000x reference)
//
#include <hip/hip_runtime.h>

// DistoLayer, fully reassociated:
//   WC[e, h*64+d'] = (1/8) * sum_d Wq[e,d] * Wk[d', h*64+d]      [64, 512]
//   A[m, c]        = sum_e x[dst[m], e] * WC[e, c]               [M, 512]
//   pair[m,k,h]    = sum_d' x[src[m,k], d'] * A[m, h*64+d']
//   hidden = relu(pair @ Wp1); logits = hidden @ Wp2             [M*K, C]
//
// N=100000, M=10000, K=32, D=64, H=8, C=64. f32; indices int32.
// disto_B is wave-per-m: NO LDS, NO barriers. Lane (k8,j) owns d'-slice
// [j*8, j*8+8) and output cols [j*8, j*8+8); 3-round shfl_xor butterfly
// over the j-octet completes the pair dot; MLP finishes lane-locally.

#define Mm 10000
#define Kk 32
#define Dd 64
#define Hh 8
#define Cc 64

constexpr int M_PER_A2 = 10;                    // 1000 blocks
constexpr size_t WC_FLOATS = 64 * 512;
constexpr size_t A_FLOATS  = (size_t)Mm * 512;
constexpr size_t WS_NEED   = (WC_FLOATS + A_FLOATS) * sizeof(float);

// ------------------------------------------------------------- wc_build
__global__ __launch_bounds__(256) void wc_build(
    const float* __restrict__ Wq,
    const float* __restrict__ Wk,
    float* __restrict__ WC)
{
    __shared__ float wq_l[16][68];
    __shared__ float wk_l[64][68];

    const int t  = threadIdx.x;
    const int e0 = blockIdx.x * 16;
    const int h  = blockIdx.y;

    {
        int r = t >> 4, q = t & 15;
        float4 v = ((const float4*)Wq)[(e0 + r) * 16 + q];
        *(float4*)&wq_l[r][q * 4] = v;
    }
    #pragma unroll
    for (int p = 0; p < 4; ++p) {
        int task = p * 256 + t;
        int dp = task >> 4, q = task & 15;
        float4 v = ((const float4*)Wk)[(size_t)dp * 128 + h * 16 + q];
        *(float4*)&wk_l[dp][q * 4] = v;
    }
    __syncthreads();

    const int dp = t & 63;
    const int eq = t >> 6;

    float4 wr[16];
    #pragma unroll
    for (int d4 = 0; d4 < 16; ++d4) wr[d4] = *(const float4*)&wk_l[dp][d4 * 4];

    #pragma unroll
    for (int i = 0; i < 4; ++i) {
        const int er = eq * 4 + i;
        float acc = 0.f;
        #pragma unroll
        for (int d4 = 0; d4 < 16; ++d4) {
            float4 qv = *(const float4*)&wq_l[er][d4 * 4];
            acc = fmaf(qv.x, wr[d4].x, acc);
            acc = fmaf(qv.y, wr[d4].y, acc);
            acc = fmaf(qv.z, wr[d4].z, acc);
            acc = fmaf(qv.w, wr[d4].w, acc);
        }
        WC[(size_t)(e0 + er) * 512 + h * 64 + dp] = acc * 0.125f;
    }
}

// ------------------------------------------------------------- disto_A2
__global__ __launch_bounds__(512) void disto_A2(
    const float* __restrict__ x,
    const int*   __restrict__ dst_idx,
    const float* __restrict__ WC,
    float* __restrict__ A)
{
    __shared__ float xr[M_PER_A2][68];

    const int t  = threadIdx.x;
    const int m0 = blockIdx.x * M_PER_A2;

    if (t < M_PER_A2 * 16) {
        int r = t >> 4, q = t & 15;
        int idx = dst_idx[m0 + r];
        float4 v = ((const float4*)x)[(size_t)idx * 16 + q];
        *(float4*)&xr[r][q * 4] = v;
    }

    float wc[64];
    #pragma unroll
    for (int e = 0; e < 64; ++e) wc[e] = WC[(size_t)e * 512 + t];

    __syncthreads();

    for (int mi = 0; mi < M_PER_A2; ++mi) {
        float acc0 = 0.f, acc1 = 0.f;
        #pragma unroll
        for (int e4 = 0; e4 < 16; ++e4) {
            float4 xv = *(const float4*)&xr[mi][e4 * 4];
            acc0 = fmaf(xv.x, wc[e4 * 4 + 0], acc0);
            acc1 = fmaf(xv.y, wc[e4 * 4 + 1], acc1);
            acc0 = fmaf(xv.z, wc[e4 * 4 + 2], acc0);
            acc1 = fmaf(xv.w, wc[e4 * 4 + 3], acc1);
        }
        A[(size_t)(m0 + mi) * 512 + t] = acc0 + acc1;
    }
}

// ------------------------------------------------------------- disto_B
// wave-per-m, LDS-free, barrier-free.
__global__ __launch_bounds__(256) void disto_B(
    const float* __restrict__ x,
    const int*   __restrict__ src_idx,
    const float* __restrict__ A,
    const float* __restrict__ Wp1,
    const float* __restrict__ Wp2,
    float* __restrict__ out)
{
    const int t  = threadIdx.x;
    const int w  = t >> 6;
    const int l  = t & 63;
    const int m  = blockIdx.x * 4 + w;
    const int j  = l & 7;          // d'-slice / output-col-group
    const int k8 = l >> 3;         // k within chunk

    // src indices for this lane's k per chunk (8 j-lanes broadcast-share)
    int idx[4];
    #pragma unroll
    for (int kc = 0; kc < 4; ++kc) idx[kc] = src_idx[m * Kk + kc * 8 + k8];

    // A-slice: a[h][i] = A[m, h*64 + j*8 + i]  (64 regs, 8-lane-broadcast loads)
    float a[8][8];
    #pragma unroll
    for (int h = 0; h < 8; ++h) {
        float4 u = ((const float4*)A)[(size_t)m * 128 + h * 16 + j * 2];
        float4 v = ((const float4*)A)[(size_t)m * 128 + h * 16 + j * 2 + 1];
        a[h][0] = u.x; a[h][1] = u.y; a[h][2] = u.z; a[h][3] = u.w;
        a[h][4] = v.x; a[h][5] = v.y; a[h][6] = v.z; a[h][7] = v.w;
    }

    // full Wp1 in regs (same addr all lanes -> broadcast, L1)
    float wp1[8][8];
    #pragma unroll
    for (int h = 0; h < 8; ++h) {
        float4 u = *(const float4*)(Wp1 + h * 8);
        float4 v = *(const float4*)(Wp1 + h * 8 + 4);
        wp1[h][0] = u.x; wp1[h][1] = u.y; wp1[h][2] = u.z; wp1[h][3] = u.w;
        wp1[h][4] = v.x; wp1[h][5] = v.y; wp1[h][6] = v.z; wp1[h][7] = v.w;
    }

    float xr0[8], xr1[8];
    auto load_x = [&](float* xr, int id) {
        const float4* p = (const float4*)(x + (size_t)id * 64 + j * 8);
        float4 u = p[0], v = p[1];
        xr[0] = u.x; xr[1] = u.y; xr[2] = u.z; xr[3] = u.w;
        xr[4] = v.x; xr[5] = v.y; xr[6] = v.z; xr[7] = v.w;
    };
    auto compute = [&](const float* xr, int kc) {
        // partial[h] over this lane's d'-slice
        float partial[8];
        #pragma unroll
        for (int h = 0; h < 8; ++h) {
            float p0 = 0.f, p1 = 0.f;
            #pragma unroll
            for (int i = 0; i < 8; i += 2) {
                p0 = fmaf(xr[i],     a[h][i],     p0);
                p1 = fmaf(xr[i + 1], a[h][i + 1], p1);
            }
            partial[h] = p0 + p1;
        }
        // butterfly over the j-octet: full pair[k, 0..7] on every lane
        #pragma unroll
        for (int s = 1; s < 8; s <<= 1) {
            #pragma unroll
            for (int h = 0; h < 8; ++h)
                partial[h] += __shfl_xor(partial[h], s, 64);
        }
        // hidden = relu(pair @ Wp1), lane-local
        float hid[8];
        #pragma unroll
        for (int jp = 0; jp < 8; ++jp) {
            float s0 = 0.f;
            #pragma unroll
            for (int h = 0; h < 8; ++h)
                s0 = fmaf(partial[h], wp1[h][jp], s0);
            hid[jp] = fmaxf(s0, 0.f);
        }
        // logits cols [j*8, j*8+8): Wp2 rows from L1 (2KB, hot)
        float lg[8] = {0,0,0,0,0,0,0,0};
        #pragma unroll
        for (int h = 0; h < 8; ++h) {
            float4 wa = ((const float4*)Wp2)[h * 16 + j * 2];
            float4 wb = ((const float4*)Wp2)[h * 16 + j * 2 + 1];
            lg[0] = fmaf(hid[h], wa.x, lg[0]);
            lg[1] = fmaf(hid[h], wa.y, lg[1]);
            lg[2] = fmaf(hid[h], wa.z, lg[2]);
            lg[3] = fmaf(hid[h], wa.w, lg[3]);
            lg[4] = fmaf(hid[h], wb.x, lg[4]);
            lg[5] = fmaf(hid[h], wb.y, lg[5]);
            lg[6] = fmaf(hid[h], wb.z, lg[6]);
            lg[7] = fmaf(hid[h], wb.w, lg[7]);
        }
        size_t row = (size_t)m * Kk + kc * 8 + k8;
        float4* o4 = (float4*)(out + row * Cc + j * 8);
        o4[0] = make_float4(lg[0], lg[1], lg[2], lg[3]);
        o4[1] = make_float4(lg[4], lg[5], lg[6], lg[7]);
    };

    load_x(xr0, idx[0]);
    load_x(xr1, idx[1]);
    compute(xr0, 0);
    load_x(xr0, idx[2]);
    compute(xr1, 1);
    load_x(xr1, idx[3]);
    compute(xr0, 2);
    compute(xr1, 3);
}

// ------------------------------------------------- fallback fused kernel
constexpr int WAVES = 4;
constexpr int PAD = 68;

__global__ __launch_bounds__(256) void disto_fused(
    const float* __restrict__ x,
    const int*   __restrict__ src_idx,
    const int*   __restrict__ dst_idx,
    const float* __restrict__ Wq,
    const float* __restrict__ Wk,
    const float* __restrict__ Wp1,
    const float* __restrict__ Wp2,
    float* __restrict__ out)
{
    __shared__ float ni_lds[WAVES][Dd];
    __shared__ float A_lds[WAVES][Hh][PAD];
    __shared__ float xs_lds[WAVES][8][PAD];
    __shared__ float wp2_lds[Hh * Cc];

    const int t = threadIdx.x;
    const int w = t >> 6;
    const int l = t & 63;
    const int m = blockIdx.x * WAVES + w;

    if (t < 128) ((float4*)wp2_lds)[t] = ((const float4*)Wp2)[t];

    const int dst = dst_idx[m];
    float xd = x[(size_t)dst * Dd + l];
    float acc1 = 0.f;
    #pragma unroll
    for (int dp = 0; dp < Dd; ++dp) {
        float xv = __shfl(xd, dp, 64);
        acc1 = fmaf(xv, Wq[dp * Dd + l], acc1);
    }
    ni_lds[w][l] = acc1;
    __syncthreads();
    {
        const float4* ni4 = (const float4*)ni_lds[w];
        const float4* wkrow = (const float4*)(Wk + (size_t)l * (Dd * Hh));
        #pragma unroll
        for (int h = 0; h < Hh; ++h) {
            float a = 0.f;
            #pragma unroll
            for (int d4 = 0; d4 < Dd / 4; ++d4) {
                float4 nv = ni4[d4];
                float4 wv = wkrow[h * (Dd / 4) + d4];
                a = fmaf(nv.x, wv.x, a);
                a = fmaf(nv.y, wv.y, a);
                a = fmaf(nv.z, wv.z, a);
                a = fmaf(nv.w, wv.w, a);
            }
            A_lds[w][h][l] = a * 0.125f;
        }
    }
    const int h_role = l & 7;
    const int k8 = l >> 3;
    float wp1r[8];
    #pragma unroll
    for (int jj = 0; jj < 8; ++jj) wp1r[jj] = Wp1[h_role * Hh + jj];
    __syncthreads();

    for (int kc = 0; kc < 4; ++kc) {
        #pragma unroll
        for (int p = 0; p < 2; ++p) {
            int task = p * 64 + l;
            int r = task >> 4;
            int jq = task & 15;
            int idx = src_idx[m * Kk + kc * 8 + r];
            float4 v = ((const float4*)x)[(size_t)idx * (Dd / 4) + jq];
            *(float4*)&xs_lds[w][r][jq * 4] = v;
        }
        __syncthreads();
        float pair = 0.f;
        {
            const float4* xsr = (const float4*)xs_lds[w][k8];
            const float4* ar  = (const float4*)A_lds[w][h_role];
            #pragma unroll
            for (int d4 = 0; d4 < Dd / 4; ++d4) {
                float4 xv = xsr[d4];
                float4 av = ar[d4];
                pair = fmaf(xv.x, av.x, pair);
                pair = fmaf(xv.y, av.y, pair);
                pair = fmaf(xv.z, av.z, pair);
                pair = fmaf(xv.w, av.w, pair);
            }
        }
        float hid[8];
        #pragma unroll
        for (int jj = 0; jj < 8; ++jj) hid[jj] = pair * wp1r[jj];
        #pragma unroll
        for (int s = 1; s < 8; s <<= 1) {
            #pragma unroll
            for (int jj = 0; jj < 8; ++jj)
                hid[jj] += __shfl_xor(hid[jj], s, 64);
        }
        #pragma unroll
        for (int jj = 0; jj < 8; ++jj) hid[jj] = fmaxf(hid[jj], 0.f);
        float lg[8] = {0,0,0,0,0,0,0,0};
        #pragma unroll
        for (int hp = 0; hp < 8; ++hp) {
            const float* wrow = &wp2_lds[hp * Cc + h_role * 8];
            float4 wa = *(const float4*)wrow;
            float4 wb = *(const float4*)(wrow + 4);
            lg[0] = fmaf(hid[hp], wa.x, lg[0]);
            lg[1] = fmaf(hid[hp], wa.y, lg[1]);
            lg[2] = fmaf(hid[hp], wa.z, lg[2]);
            lg[3] = fmaf(hid[hp], wa.w, lg[3]);
            lg[4] = fmaf(hid[hp], wb.x, lg[4]);
            lg[5] = fmaf(hid[hp], wb.y, lg[5]);
            lg[6] = fmaf(hid[hp], wb.z, lg[6]);
            lg[7] = fmaf(hid[hp], wb.w, lg[7]);
        }
        size_t row = (size_t)(m * Kk + kc * 8 + k8);
        float4* o4 = (float4*)(out + row * Cc + h_role * 8);
        o4[0] = make_float4(lg[0], lg[1], lg[2], lg[3]);
        o4[1] = make_float4(lg[4], lg[5], lg[6], lg[7]);
        __syncthreads();
    }
}

extern "C" void kernel_launch(void* const* d_in, const int* in_sizes, int n_in,
                              void* d_out, int out_size, void* d_ws, size_t ws_size,
                              hipStream_t stream) {
    const float* x       = (const float*)d_in[0];
    const int*   src_idx = (const int*)  d_in[1];
    const int*   dst_idx = (const int*)  d_in[2];
    const float* Wq      = (const float*)d_in[3];
    const float* Wk      = (const float*)d_in[4];
    const float* Wp1     = (const float*)d_in[5];
    const float* Wp2     = (const float*)d_in[6];
    float* out = (float*)d_out;

    if (ws_size >= WS_NEED) {
        float* WC = (float*)d_ws;
        float* A  = WC + WC_FLOATS;
        wc_build<<<dim3(4, 8), dim3(256), 0, stream>>>(Wq, Wk, WC);
        disto_A2<<<dim3(Mm / M_PER_A2), dim3(512), 0, stream>>>(x, dst_idx, WC, A);
        disto_B<<<dim3(Mm / 4), dim3(256), 0, stream>>>(x, src_idx, A, Wp1, Wp2, out);
    } else {
        disto_fused<<<dim3(Mm / WAVES), dim3(256), 0, stream>>>(
            x, src_idx, dst_idx, Wq, Wk, Wp1, Wp2, out);
    }
}

// Round 6
// 160.446 us; speedup vs baseline: 1.1038x; 1.1038x over previous
//
#include <hip/hip_runtime.h>

// DistoLayer, fully reassociated:
//   WC[e, h*64+d'] = (1/8) * sum_d Wq[e,d] * Wk[d', h*64+d]      [64, 512]
//   A[m, c]        = sum_e x[dst[m], e] * WC[e, c]    (LDS only, never stored)
//   pair[m,k,h]    = sum_d' x[src[m,k], d'] * A[m, h*64+d']
//   hidden = relu(pair @ Wp1); logits = hidden @ Wp2             [M*K, C]
//
// disto_AB: 625 blocks x 512 thr; block owns 16 m's (8 m-pairs).
// Per pair: A-compute (WC col cached in 64 VGPR) -> barrier -> B-compute
// (round-2 proven h_role/k8 wave layout) -> write prefetched gathers ->
// barrier.  x-gathers for pair p+1 issued to REGS before p's compute
// (T14 issue-early/write-late), double-buffered LDS.

#define Mm 10000
#define Kk 32
#define Dd 64
#define Hh 8
#define Cc 64

constexpr int MB_ = 16;      // m's per AB block
constexpr int PAIRS = 8;
constexpr size_t WC_FLOATS = 64 * 512;
constexpr size_t WS_NEED = WC_FLOATS * sizeof(float);   // 128 KB

// ------------------------------------------------------------- wc_build
__global__ __launch_bounds__(256) void wc_build(
    const float* __restrict__ Wq,
    const float* __restrict__ Wk,
    float* __restrict__ WC)
{
    __shared__ float wq_l[16][68];
    __shared__ float wk_l[64][68];

    const int t  = threadIdx.x;
    const int e0 = blockIdx.x * 16;
    const int h  = blockIdx.y;

    {
        int r = t >> 4, q = t & 15;
        float4 v = ((const float4*)Wq)[(e0 + r) * 16 + q];
        *(float4*)&wq_l[r][q * 4] = v;
    }
    #pragma unroll
    for (int p = 0; p < 4; ++p) {
        int task = p * 256 + t;
        int dp = task >> 4, q = task & 15;
        float4 v = ((const float4*)Wk)[(size_t)dp * 128 + h * 16 + q];
        *(float4*)&wk_l[dp][q * 4] = v;
    }
    __syncthreads();

    const int dp = t & 63;
    const int eq = t >> 6;

    float4 wr[16];
    #pragma unroll
    for (int d4 = 0; d4 < 16; ++d4) wr[d4] = *(const float4*)&wk_l[dp][d4 * 4];

    #pragma unroll
    for (int i = 0; i < 4; ++i) {
        const int er = eq * 4 + i;
        float acc = 0.f;
        #pragma unroll
        for (int d4 = 0; d4 < 16; ++d4) {
            float4 qv = *(const float4*)&wq_l[er][d4 * 4];
            acc = fmaf(qv.x, wr[d4].x, acc);
            acc = fmaf(qv.y, wr[d4].y, acc);
            acc = fmaf(qv.z, wr[d4].z, acc);
            acc = fmaf(qv.w, wr[d4].w, acc);
        }
        WC[(size_t)(e0 + er) * 512 + h * 64 + dp] = acc * 0.125f;
    }
}

// ------------------------------------------------------------- disto_AB
__global__ __launch_bounds__(512) void disto_AB(
    const float* __restrict__ x,
    const int*   __restrict__ src_idx,
    const int*   __restrict__ dst_idx,
    const float* __restrict__ WC,
    const float* __restrict__ Wp1,
    const float* __restrict__ Wp2,
    float* __restrict__ out)
{
    __shared__ float xs[2][64][68];    // [buf][pair-local row][d'] gathered src rows
    __shared__ float dstx[2][2][68];   // [buf][ml][e] gathered dst rows
    __shared__ float a_lds[2][8][68];  // [ml][h][d']
    __shared__ float wp2_l[512];
    __shared__ int   idx_l[MB_ * Kk];  // 512 src indices
    __shared__ int   didx_l[MB_];      // 16 dst indices

    const int t  = threadIdx.x;
    const int m0 = blockIdx.x * MB_;

    // ---- prologue: stage indices + Wp2, cache WC column t ----
    idx_l[t] = src_idx[m0 * Kk + t];
    if (t < MB_) didx_l[t] = dst_idx[m0 + t];
    if (t < 128) ((float4*)wp2_l)[t] = ((const float4*)Wp2)[t];

    float wc[64];
    #pragma unroll
    for (int e = 0; e < 64; ++e) wc[e] = WC[(size_t)e * 512 + t];

    __syncthreads();   // idx_l ready

    // ---- gather pair 0 directly to LDS buf 0 ----
    #pragma unroll
    for (int p = 0; p < 2; ++p) {
        int task = p * 512 + t;
        int r = task >> 4, q = task & 15;
        float4 v = ((const float4*)x)[(size_t)idx_l[r] * 16 + q];
        *(float4*)&xs[0][r][q * 4] = v;
    }
    if (t < 32) {
        float4 v = ((const float4*)x)[(size_t)didx_l[t >> 4] * 16 + (t & 15)];
        *(float4*)&dstx[0][t >> 4][(t & 15) * 4] = v;
    }

    // wave roles for B-phase
    const int l = t & 63, w = t >> 6;
    const int ml_w = w >> 2, ch = w & 3;      // wave -> (m-local, k-chunk)
    const int h_role = l & 7, k8 = l >> 3;
    float wp1r[8];
    #pragma unroll
    for (int j = 0; j < 8; ++j) wp1r[j] = Wp1[h_role * Hh + j];

    __syncthreads();   // buf 0 ready

    const int hh = t >> 6, dp = t & 63;       // A-compute: c = hh*64+dp = t
    int cur = 0;

    for (int p = 0; p < PAIRS; ++p) {
        // ---- 1) issue prefetch for pair p+1 (global -> regs, write later) ----
        float4 nx0, nx1, nd;
        const bool havepf = (p + 1 < PAIRS);
        const int r0 = t >> 4, q0 = t & 15;           // rows 0..31
        const int r1 = 32 + (t >> 4);                 // rows 32..63
        if (havepf) {
            const int base = (p + 1) * 64;
            nx0 = ((const float4*)x)[(size_t)idx_l[base + r0] * 16 + q0];
            nx1 = ((const float4*)x)[(size_t)idx_l[base + r1] * 16 + q0];
            if (t < 32)
                nd = ((const float4*)x)[(size_t)didx_l[(p + 1) * 2 + (t >> 4)] * 16 + (t & 15)];
        }

        // ---- 2) A-compute for pair p (overlaps in-flight loads) ----
        #pragma unroll
        for (int ml = 0; ml < 2; ++ml) {
            float a0 = 0.f, a1 = 0.f;
            #pragma unroll
            for (int e4 = 0; e4 < 16; ++e4) {
                float4 xv = *(const float4*)&dstx[cur][ml][e4 * 4];  // broadcast
                a0 = fmaf(xv.x, wc[e4 * 4 + 0], a0);
                a1 = fmaf(xv.y, wc[e4 * 4 + 1], a1);
                a0 = fmaf(xv.z, wc[e4 * 4 + 2], a0);
                a1 = fmaf(xv.w, wc[e4 * 4 + 3], a1);
            }
            a_lds[ml][hh][dp] = a0 + a1;
        }
        __syncthreads();   // a_lds ready (xs[cur] ready from prev barrier)

        // ---- 3) B-compute: wave (ml_w, ch); lane (h_role, k8) ----
        {
            float pair = 0.f;
            const float4* xr = (const float4*)xs[cur][ml_w * 32 + ch * 8 + k8];
            const float4* ar = (const float4*)a_lds[ml_w][h_role];
            #pragma unroll
            for (int d4 = 0; d4 < 16; ++d4) {
                float4 xv = xr[d4];
                float4 av = ar[d4];
                pair = fmaf(xv.x, av.x, pair);
                pair = fmaf(xv.y, av.y, pair);
                pair = fmaf(xv.z, av.z, pair);
                pair = fmaf(xv.w, av.w, pair);
            }
            float hid[8];
            #pragma unroll
            for (int j = 0; j < 8; ++j) hid[j] = pair * wp1r[j];
            #pragma unroll
            for (int s = 1; s < 8; s <<= 1) {
                #pragma unroll
                for (int j = 0; j < 8; ++j)
                    hid[j] += __shfl_xor(hid[j], s, 64);
            }
            #pragma unroll
            for (int j = 0; j < 8; ++j) hid[j] = fmaxf(hid[j], 0.f);

            float lg[8] = {0, 0, 0, 0, 0, 0, 0, 0};
            #pragma unroll
            for (int hp = 0; hp < 8; ++hp) {
                const float* wrow = &wp2_l[hp * Cc + h_role * 8];
                float4 wa = *(const float4*)wrow;
                float4 wb = *(const float4*)(wrow + 4);
                lg[0] = fmaf(hid[hp], wa.x, lg[0]);
                lg[1] = fmaf(hid[hp], wa.y, lg[1]);
                lg[2] = fmaf(hid[hp], wa.z, lg[2]);
                lg[3] = fmaf(hid[hp], wa.w, lg[3]);
                lg[4] = fmaf(hid[hp], wb.x, lg[4]);
                lg[5] = fmaf(hid[hp], wb.y, lg[5]);
                lg[6] = fmaf(hid[hp], wb.z, lg[6]);
                lg[7] = fmaf(hid[hp], wb.w, lg[7]);
            }
            const int m = m0 + p * 2 + ml_w;
            size_t row = (size_t)m * Kk + ch * 8 + k8;
            float4* o4 = (float4*)(out + row * Cc + h_role * 8);
            o4[0] = make_float4(lg[0], lg[1], lg[2], lg[3]);
            o4[1] = make_float4(lg[4], lg[5], lg[6], lg[7]);
        }

        // ---- 4) write prefetched regs into the other buffer ----
        if (havepf) {
            const int nxt = cur ^ 1;
            *(float4*)&xs[nxt][r0][q0 * 4] = nx0;
            *(float4*)&xs[nxt][r1][q0 * 4] = nx1;
            if (t < 32)
                *(float4*)&dstx[nxt][t >> 4][(t & 15) * 4] = nd;
        }
        __syncthreads();   // next buf ready; all waves done with a_lds/xs[cur]
        cur ^= 1;
    }
}

// ------------------------------------------------- fallback fused kernel
constexpr int WAVES = 4;
constexpr int PAD = 68;

__global__ __launch_bounds__(256) void disto_fused(
    const float* __restrict__ x,
    const int*   __restrict__ src_idx,
    const int*   __restrict__ dst_idx,
    const float* __restrict__ Wq,
    const float* __restrict__ Wk,
    const float* __restrict__ Wp1,
    const float* __restrict__ Wp2,
    float* __restrict__ out)
{
    __shared__ float ni_lds[WAVES][Dd];
    __shared__ float A_lds[WAVES][Hh][PAD];
    __shared__ float xs_lds[WAVES][8][PAD];
    __shared__ float wp2_lds[Hh * Cc];

    const int t = threadIdx.x;
    const int w = t >> 6;
    const int l = t & 63;
    const int m = blockIdx.x * WAVES + w;

    if (t < 128) ((float4*)wp2_lds)[t] = ((const float4*)Wp2)[t];

    const int dst = dst_idx[m];
    float xd = x[(size_t)dst * Dd + l];
    float acc1 = 0.f;
    #pragma unroll
    for (int dp = 0; dp < Dd; ++dp) {
        float xv = __shfl(xd, dp, 64);
        acc1 = fmaf(xv, Wq[dp * Dd + l], acc1);
    }
    ni_lds[w][l] = acc1;
    __syncthreads();
    {
        const float4* ni4 = (const float4*)ni_lds[w];
        const float4* wkrow = (const float4*)(Wk + (size_t)l * (Dd * Hh));
        #pragma unroll
        for (int h = 0; h < Hh; ++h) {
            float a = 0.f;
            #pragma unroll
            for (int d4 = 0; d4 < Dd / 4; ++d4) {
                float4 nv = ni4[d4];
                float4 wv = wkrow[h * (Dd / 4) + d4];
                a = fmaf(nv.x, wv.x, a);
                a = fmaf(nv.y, wv.y, a);
                a = fmaf(nv.z, wv.z, a);
                a = fmaf(nv.w, wv.w, a);
            }
            A_lds[w][h][l] = a * 0.125f;
        }
    }
    const int h_role = l & 7;
    const int k8 = l >> 3;
    float wp1r[8];
    #pragma unroll
    for (int j = 0; j < 8; ++j) wp1r[j] = Wp1[h_role * Hh + j];
    __syncthreads();

    for (int kc = 0; kc < 4; ++kc) {
        #pragma unroll
        for (int p = 0; p < 2; ++p) {
            int task = p * 64 + l;
            int r = task >> 4;
            int jq = task & 15;
            int idx = src_idx[m * Kk + kc * 8 + r];
            float4 v = ((const float4*)x)[(size_t)idx * (Dd / 4) + jq];
            *(float4*)&xs_lds[w][r][jq * 4] = v;
        }
        __syncthreads();
        float pair = 0.f;
        {
            const float4* xsr = (const float4*)xs_lds[w][k8];
            const float4* ar  = (const float4*)A_lds[w][h_role];
            #pragma unroll
            for (int d4 = 0; d4 < Dd / 4; ++d4) {
                float4 xv = xsr[d4];
                float4 av = ar[d4];
                pair = fmaf(xv.x, av.x, pair);
                pair = fmaf(xv.y, av.y, pair);
                pair = fmaf(xv.z, av.z, pair);
                pair = fmaf(xv.w, av.w, pair);
            }
        }
        float hid[8];
        #pragma unroll
        for (int j = 0; j < 8; ++j) hid[j] = pair * wp1r[j];
        #pragma unroll
        for (int s = 1; s < 8; s <<= 1) {
            #pragma unroll
            for (int j = 0; j < 8; ++j)
                hid[j] += __shfl_xor(hid[j], s, 64);
        }
        #pragma unroll
        for (int j = 0; j < 8; ++j) hid[j] = fmaxf(hid[j], 0.f);
        float lg[8] = {0,0,0,0,0,0,0,0};
        #pragma unroll
        for (int hp = 0; hp < 8; ++hp) {
            const float* wrow = &wp2_lds[hp * Cc + h_role * 8];
            float4 wa = *(const float4*)wrow;
            float4 wb = *(const float4*)(wrow + 4);
            lg[0] = fmaf(hid[hp], wa.x, lg[0]);
            lg[1] = fmaf(hid[hp], wa.y, lg[1]);
            lg[2] = fmaf(hid[hp], wa.z, lg[2]);
            lg[3] = fmaf(hid[hp], wa.w, lg[3]);
            lg[4] = fmaf(hid[hp], wb.x, lg[4]);
            lg[5] = fmaf(hid[hp], wb.y, lg[5]);
            lg[6] = fmaf(hid[hp], wb.z, lg[6]);
            lg[7] = fmaf(hid[hp], wb.w, lg[7]);
        }
        size_t row = (size_t)(m * Kk + kc * 8 + k8);
        float4* o4 = (float4*)(out + row * Cc + h_role * 8);
        o4[0] = make_float4(lg[0], lg[1], lg[2], lg[3]);
        o4[1] = make_float4(lg[4], lg[5], lg[6], lg[7]);
        __syncthreads();
    }
}

extern "C" void kernel_launch(void* const* d_in, const int* in_sizes, int n_in,
                              void* d_out, int out_size, void* d_ws, size_t ws_size,
                              hipStream_t stream) {
    const float* x       = (const float*)d_in[0];
    const int*   src_idx = (const int*)  d_in[1];
    const int*   dst_idx = (const int*)  d_in[2];
    const float* Wq      = (const float*)d_in[3];
    const float* Wk      = (const float*)d_in[4];
    const float* Wp1     = (const float*)d_in[5];
    const float* Wp2     = (const float*)d_in[6];
    float* out = (float*)d_out;

    if (ws_size >= WS_NEED) {
        float* WC = (float*)d_ws;
        wc_build<<<dim3(4, 8), dim3(256), 0, stream>>>(Wq, Wk, WC);
        disto_AB<<<dim3(Mm / MB_), dim3(512), 0, stream>>>(
            x, src_idx, dst_idx, WC, Wp1, Wp2, out);
    } else {
        disto_fused<<<dim3(Mm / WAVES), dim3(256), 0, stream>>>(
            x, src_idx, dst_idx, Wq, Wk, Wp1, Wp2, out);
    }
}